// Round 18
// baseline (428.002 us; speedup 1.0000x reference)
//
#include <hip/hip_runtime.h>
#include <hip/hip_bf16.h>

#define LN_EPS 1e-5f

typedef __attribute__((ext_vector_type(8))) short bf16x8;
typedef __attribute__((ext_vector_type(4))) float f32x4;

__device__ __forceinline__ short f2bf(float x) {
    union { float f; unsigned u; } v; v.f = x;
    unsigned r = v.u + 0x7fff + ((v.u >> 16) & 1);   // RNE to bf16
    return (short)(r >> 16);
}
__device__ __forceinline__ short2 cvt2(float a, float b) {
    // scalar RNE casts; compiler may fuse to v_cvt_pk_bf16_f32 (m240)
    short2 p; p.x = f2bf(a); p.y = f2bf(b); return p;
}

#define H_STRIDE 272   // 256 data bytes + 16 pad

// Barrier-minimal structure: NO input staging. Layer-1 B-fragments load
// straight from global (per-lane 2x float4, 16 rows x 128B coalesced per
// instruction), depth-2 register pipeline, cvt to bf16 in-reg. The rl
// orientation reuses chunk-c data against W1 chunk (c+4)&7 (same as R12).
// hbuf exchange + parity-buffered lnp -> only 2 barriers per tile.
// Block = 256 threads = 4 waves; wave w owns features [32w, 32w+32).
// Each iteration: 32 edges -> 64 output rows (32 lr + 32 rl).
__global__ __launch_bounds__(256) void mpnn_mfma(
    const float* __restrict__ inR, const float* __restrict__ inL,
    const float* __restrict__ W1, const float* __restrict__ b1,
    const float* __restrict__ W2, const float* __restrict__ b2,
    const float* __restrict__ gamma, const float* __restrict__ beta,
    float* __restrict__ out, int E, int niters)
{
    __shared__ __align__(16) char hbuf[64 * H_STRIDE];  // h1 exchange (bf16)
    __shared__ float2 lnp[2][4][4][16];                 // parity-buffered LN partials
    __shared__ __align__(16) float bgl[4][128];         // b1, b2, gamma, beta

    const int tid  = threadIdx.x;
    const int lane = tid & 63;
    const int wave = tid >> 6;
    const int r    = lane & 15;
    const int q    = lane >> 4;

    if (tid < 128) {
        bgl[0][tid] = b1[tid];
        bgl[1][tid] = b2[tid];
        bgl[2][tid] = gamma[tid];
        bgl[3][tid] = beta[tid];
    }

    // ---- weight fragments from fp32 globals (once per block, L2-resident) ----
    bf16x8 A1[2][8], A2[2][4];
#pragma unroll
    for (int t = 0; t < 2; ++t) {
        const int fr = wave * 32 + t * 16 + r;
#pragma unroll
        for (int c = 0; c < 8; ++c)
#pragma unroll
            for (int i = 0; i < 8; ++i)
                A1[t][c][i] = f2bf(W1[(c * 32 + q * 8 + i) * 128 + fr]);
#pragma unroll
        for (int c = 0; c < 4; ++c)
#pragma unroll
            for (int i = 0; i < 8; ++i)
                A2[t][c][i] = f2bf(W2[(c * 32 + q * 8 + i) * 128 + fr]);
    }
    __syncthreads();   // bgl ready

    int par = 0;
    for (int it = blockIdx.x; it < niters; it += gridDim.x, par ^= 1) {
        const int e0 = it * 32;
        // per-lane source rows for the two edge-tiles (clamped; stores guarded)
        long r0 = (long)e0 + r;      if (r0 >= E) r0 = E - 1;
        long r1 = (long)e0 + 16 + r; if (r1 >= E) r1 = E - 1;
        const long o0 = r0 * 128, o1 = r1 * 128;

        // ---- layer 1: B-fragments direct from global, depth-2 pipeline ----
        f32x4 acc[2][4];
#pragma unroll
        for (int t = 0; t < 2; ++t)
#pragma unroll
            for (int u = 0; u < 4; ++u)
                acc[t][u] = f32x4{0.f, 0.f, 0.f, 0.f};

        float4 fb[2][4];   // [parity][x0lo,x0hi,x1lo,x1hi] — static indexing only
        {
            const float* s = inL;  // chunk 0 -> left half, offset q*8
            fb[0][0] = *(const float4*)(s + o0 + q * 8);
            fb[0][1] = *(const float4*)(s + o0 + q * 8 + 4);
            fb[0][2] = *(const float4*)(s + o1 + q * 8);
            fb[0][3] = *(const float4*)(s + o1 + q * 8 + 4);
        }
#pragma unroll
        for (int c = 0; c < 8; ++c) {
            if (c < 7) {
                const int cn = c + 1;
                const float* s = (cn < 4) ? inL : inR;
                const int off = (cn & 3) * 32 + q * 8;
                fb[(c + 1) & 1][0] = *(const float4*)(s + o0 + off);
                fb[(c + 1) & 1][1] = *(const float4*)(s + o0 + off + 4);
                fb[(c + 1) & 1][2] = *(const float4*)(s + o1 + off);
                fb[(c + 1) & 1][3] = *(const float4*)(s + o1 + off + 4);
            }
            const float4 a0 = fb[c & 1][0], a1 = fb[c & 1][1];
            const float4 a2v = fb[c & 1][2], a3v = fb[c & 1][3];
            bf16x8 x0, x1;
            {
                short2 p;
                p = cvt2(a0.x, a0.y); x0[0] = p.x; x0[1] = p.y;
                p = cvt2(a0.z, a0.w); x0[2] = p.x; x0[3] = p.y;
                p = cvt2(a1.x, a1.y); x0[4] = p.x; x0[5] = p.y;
                p = cvt2(a1.z, a1.w); x0[6] = p.x; x0[7] = p.y;
                p = cvt2(a2v.x, a2v.y); x1[0] = p.x; x1[1] = p.y;
                p = cvt2(a2v.z, a2v.w); x1[2] = p.x; x1[3] = p.y;
                p = cvt2(a3v.x, a3v.y); x1[4] = p.x; x1[5] = p.y;
                p = cvt2(a3v.z, a3v.w); x1[6] = p.x; x1[7] = p.y;
            }
            const int crl = (c + 4) & 7;
#pragma unroll
            for (int t = 0; t < 2; ++t) {
                acc[t][0] = __builtin_amdgcn_mfma_f32_16x16x32_bf16(A1[t][c],   x0, acc[t][0], 0, 0, 0);
                acc[t][1] = __builtin_amdgcn_mfma_f32_16x16x32_bf16(A1[t][c],   x1, acc[t][1], 0, 0, 0);
                acc[t][2] = __builtin_amdgcn_mfma_f32_16x16x32_bf16(A1[t][crl], x0, acc[t][2], 0, 0, 0);
                acc[t][3] = __builtin_amdgcn_mfma_f32_16x16x32_bf16(A1[t][crl], x1, acc[t][3], 0, 0, 0);
            }
        }

        // ---- h1 = relu(. + b1) -> hbuf; erow: [0,32)=lr, [32,64)=rl ----
#pragma unroll
        for (int t = 0; t < 2; ++t) {
            const int fq = wave * 32 + t * 16 + q * 4;
            const float4 b1v = *(const float4*)(&bgl[0][fq]);
#pragma unroll
            for (int v = 0; v < 4; ++v) {
                const f32x4 a = acc[t][v];
                short4 s;
                short2 p;
                p = cvt2(fmaxf(a[0] + b1v.x, 0.f), fmaxf(a[1] + b1v.y, 0.f)); s.x = p.x; s.y = p.y;
                p = cvt2(fmaxf(a[2] + b1v.z, 0.f), fmaxf(a[3] + b1v.w, 0.f)); s.z = p.x; s.w = p.y;
                *(short4*)(&hbuf[(v * 16 + r) * H_STRIDE + fq * 2]) = s;
            }
        }
        __syncthreads();   // (A) hbuf ready (prev writes protected by prev (B))

        // ---- layer 2: reuse acc ----
#pragma unroll
        for (int t = 0; t < 2; ++t)
#pragma unroll
            for (int v = 0; v < 4; ++v) acc[t][v] = f32x4{0.f, 0.f, 0.f, 0.f};
#pragma unroll
        for (int c = 0; c < 4; ++c) {
#pragma unroll
            for (int v = 0; v < 4; ++v) {
                const bf16x8 y = *(const bf16x8*)(&hbuf[(v * 16 + r) * H_STRIDE + c * 64 + q * 16]);
#pragma unroll
                for (int t = 0; t < 2; ++t)
                    acc[t][v] = __builtin_amdgcn_mfma_f32_16x16x32_bf16(A2[t][c], y, acc[t][v], 0, 0, 0);
            }
        }

        // ---- bias + relu + LN partials ----
        float s1[4] = {0.f, 0.f, 0.f, 0.f}, s2[4] = {0.f, 0.f, 0.f, 0.f};
#pragma unroll
        for (int t = 0; t < 2; ++t) {
            const int fq = wave * 32 + t * 16 + q * 4;
            const float4 b2v = *(const float4*)(&bgl[1][fq]);
#pragma unroll
            for (int v = 0; v < 4; ++v) {
                f32x4 a = acc[t][v];
                a[0] = fmaxf(a[0] + b2v.x, 0.f);
                a[1] = fmaxf(a[1] + b2v.y, 0.f);
                a[2] = fmaxf(a[2] + b2v.z, 0.f);
                a[3] = fmaxf(a[3] + b2v.w, 0.f);
                acc[t][v] = a;
                s1[v] += a[0] + a[1] + a[2] + a[3];
                s2[v] += a[0] * a[0] + a[1] * a[1] + a[2] * a[2] + a[3] * a[3];
            }
        }
#pragma unroll
        for (int v = 0; v < 4; ++v) {
            s1[v] += __shfl_xor(s1[v], 16);
            s1[v] += __shfl_xor(s1[v], 32);
            s2[v] += __shfl_xor(s2[v], 16);
            s2[v] += __shfl_xor(s2[v], 32);
        }
        if (lane < 16) {
#pragma unroll
            for (int v = 0; v < 4; ++v)
                lnp[par][wave][v][lane] = make_float2(s1[v], s2[v]);
        }
        __syncthreads();   // (B) lnp[par] ready; all hbuf reads done

        // ---- finalize LN + fp32 stores ----
#pragma unroll
        for (int v = 0; v < 4; ++v) {
            float S1 = 0.f, S2 = 0.f;
#pragma unroll
            for (int w = 0; w < 4; ++w) {
                const float2 p = lnp[par][w][v][r];
                S1 += p.x; S2 += p.y;
            }
            const float mu  = S1 * (1.f / 128.f);
            const float var = S2 * (1.f / 128.f) - mu * mu;
            const float rs  = rsqrtf(var + LN_EPS);
            const int el = (v & 1) * 16 + r;
            const bool ok = (e0 + el) < E;
            const long orow = ((v < 2) ? 0L : (long)E) + e0 + el;
#pragma unroll
            for (int t = 0; t < 2; ++t) {
                const int fq = wave * 32 + t * 16 + q * 4;
                const float4 gv = *(const float4*)(&bgl[2][fq]);
                const float4 bv = *(const float4*)(&bgl[3][fq]);
                const f32x4 a = acc[t][v];
                float4 o;
                o.x = (a[0] - mu) * rs * gv.x + bv.x;
                o.y = (a[1] - mu) * rs * gv.y + bv.y;
                o.z = (a[2] - mu) * rs * gv.z + bv.z;
                o.w = (a[3] - mu) * rs * gv.w + bv.w;
                if (ok)
                    *(float4*)(out + orow * 128 + fq) = o;
            }
        }
    }
}

extern "C" void kernel_launch(void* const* d_in, const int* in_sizes, int n_in,
                              void* d_out, int out_size, void* d_ws, size_t ws_size,
                              hipStream_t stream) {
    // Validated interface: dict order, fp32 inputs, fp32 output.
    const float* inR   = (const float*)d_in[0];
    const float* inL   = (const float*)d_in[1];
    const float* W1    = (const float*)d_in[2];
    const float* b1    = (const float*)d_in[3];
    const float* W2    = (const float*)d_in[4];
    const float* b2    = (const float*)d_in[5];
    const float* gamma = (const float*)d_in[6];
    const float* beta  = (const float*)d_in[7];
    const int E = in_sizes[0] / 128;

    const int niters = (E + 31) / 32;
    const int d = (niters + 2047) / 2048;        // tiles per block (balanced)
    const int grid = (niters + d - 1) / d;
    mpnn_mfma<<<grid, 256, 0, stream>>>(inR, inL, W1, b1, W2, b2, gamma, beta,
                                        (float*)d_out, E, niters);
}

// Round 19
// 312.149 us; speedup vs baseline: 1.3711x; 1.3711x over previous
//
#include <hip/hip_runtime.h>
#include <hip/hip_bf16.h>

#define LN_EPS 1e-5f

typedef __attribute__((ext_vector_type(8))) short bf16x8;
typedef __attribute__((ext_vector_type(4))) float f32x4;

__device__ __forceinline__ short f2bf(float x) {
    union { float f; unsigned u; } v; v.f = x;
    unsigned r = v.u + 0x7fff + ((v.u >> 16) & 1);   // RNE to bf16
    return (short)(r >> 16);
}

#define IN_STRIDE 528   // 512 data bytes + 16 pad
#define H_STRIDE  272   // 256 data bytes + 16 pad

// R12 schedule with 64-edge tiles (was 32): same 4 barriers per tile cover
// 2x the bytes/MFMA -> half the barrier-drain cost per byte. Residency
// unchanged (2 blocks/CU, register-capped). Bias/gamma/beta in registers
// (R12 style); acc reused across L1/L2 (R16's safe merge).
// Block = 256 threads = 4 waves; wave w owns features [32w, 32w+32).
// Each iteration: 64 edges -> 128 output rows (64 lr + 64 rl).
__global__ __launch_bounds__(256) void mpnn_mfma(
    const float* __restrict__ inR, const float* __restrict__ inL,
    const float* __restrict__ W1, const float* __restrict__ b1,
    const float* __restrict__ W2, const float* __restrict__ b2,
    const float* __restrict__ gamma, const float* __restrict__ beta,
    float* __restrict__ out, int E, int niters)
{
    __shared__ __align__(16) char inA[64 * IN_STRIDE];   // 64 edges x 256 k (bf16)
    __shared__ __align__(16) char hbuf[128 * H_STRIDE];  // 128 erows x 128 f (bf16)
    __shared__ float2 lnp[4][8][16];                     // [wave][v][r] = (sum, sumsq)

    const int tid  = threadIdx.x;
    const int lane = tid & 63;
    const int wave = tid >> 6;
    const int r    = lane & 15;
    const int q    = lane >> 4;

    // ---- weight fragments + per-feature vectors (once per block) ----
    bf16x8 A1[2][8], A2[2][4];
    float4 b1v[2], b2v[2], gv[2], bv[2];
#pragma unroll
    for (int t = 0; t < 2; ++t) {
        const int fr = wave * 32 + t * 16 + r;
#pragma unroll
        for (int c = 0; c < 8; ++c)
#pragma unroll
            for (int i = 0; i < 8; ++i)
                A1[t][c][i] = f2bf(W1[(c * 32 + q * 8 + i) * 128 + fr]);
#pragma unroll
        for (int c = 0; c < 4; ++c)
#pragma unroll
            for (int i = 0; i < 8; ++i)
                A2[t][c][i] = f2bf(W2[(c * 32 + q * 8 + i) * 128 + fr]);
        const int fq = wave * 32 + t * 16 + q * 4;
        b1v[t] = *(const float4*)(b1 + fq);
        b2v[t] = *(const float4*)(b2 + fq);
        gv[t]  = *(const float4*)(gamma + fq);
        bv[t]  = *(const float4*)(beta + fq);
    }

    for (int it = blockIdx.x; it < niters; it += gridDim.x) {
        const int e0 = it * 64;
        __syncthreads();   // (0) prev iteration's inA/lnp readers done

        // ---- stage 64 edges x 256 k as bf16 (fp32 loads, 16B LDS writes) ----
#pragma unroll
        for (int j = 0; j < 8; ++j) {
            const int idx = j * 256 + tid;       // [0,2048) = [e 0..63][hw][c8 0..15]
            const int e  = idx >> 5;
            const int hw = (idx >> 4) & 1;       // 0: left half (k<128), 1: right half
            const int c8 = idx & 15;             // 8-float group within half-row
            int ee = e0 + e; if (ee >= E) ee = E - 1;
            const float* src = hw ? inR : inL;   // msg = left || right
            const float4 v0 = *(const float4*)(src + (long)ee * 128 + c8 * 8);
            const float4 v1 = *(const float4*)(src + (long)ee * 128 + c8 * 8 + 4);
            bf16x8 s;
            s[0] = f2bf(v0.x); s[1] = f2bf(v0.y); s[2] = f2bf(v0.z); s[3] = f2bf(v0.w);
            s[4] = f2bf(v1.x); s[5] = f2bf(v1.y); s[6] = f2bf(v1.z); s[7] = f2bf(v1.w);
            *(bf16x8*)(&inA[e * IN_STRIDE + hw * 256 + c8 * 16]) = s;
        }
        __syncthreads();   // (1) inA ready

        // ---- layer 1: lr uses W1 chunk c with data chunk c; rl uses (c+4)&7 ----
        f32x4 acc[2][8];   // [t][v]: v<4 lr e-tiles, v>=4 rl e-tiles
#pragma unroll
        for (int t = 0; t < 2; ++t)
#pragma unroll
            for (int v = 0; v < 8; ++v)
                acc[t][v] = f32x4{0.f, 0.f, 0.f, 0.f};
#pragma unroll
        for (int c = 0; c < 8; ++c) {
            bf16x8 x[4];
#pragma unroll
            for (int u = 0; u < 4; ++u)
                x[u] = *(const bf16x8*)(&inA[(u * 16 + r) * IN_STRIDE + c * 64 + q * 16]);
            const int crl = (c + 4) & 7;
#pragma unroll
            for (int t = 0; t < 2; ++t)
#pragma unroll
                for (int u = 0; u < 4; ++u) {
                    acc[t][u]     = __builtin_amdgcn_mfma_f32_16x16x32_bf16(A1[t][c],   x[u], acc[t][u],     0, 0, 0);
                    acc[t][u + 4] = __builtin_amdgcn_mfma_f32_16x16x32_bf16(A1[t][crl], x[u], acc[t][u + 4], 0, 0, 0);
                }
        }

        // ---- h1 = relu(. + b1) -> hbuf; erow: [0,64)=lr, [64,128)=rl ----
#pragma unroll
        for (int t = 0; t < 2; ++t) {
            const int fq = wave * 32 + t * 16 + q * 4;
#pragma unroll
            for (int v = 0; v < 8; ++v) {
                const f32x4 a = acc[t][v];
                short4 s;
                s.x = f2bf(fmaxf(a[0] + b1v[t].x, 0.f));
                s.y = f2bf(fmaxf(a[1] + b1v[t].y, 0.f));
                s.z = f2bf(fmaxf(a[2] + b1v[t].z, 0.f));
                s.w = f2bf(fmaxf(a[3] + b1v[t].w, 0.f));
                *(short4*)(&hbuf[(v * 16 + r) * H_STRIDE + fq * 2]) = s;
            }
        }
        __syncthreads();   // (2) hbuf ready; all inA reads complete

        // ---- layer 2: reuse acc ----
#pragma unroll
        for (int t = 0; t < 2; ++t)
#pragma unroll
            for (int v = 0; v < 8; ++v) acc[t][v] = f32x4{0.f, 0.f, 0.f, 0.f};
#pragma unroll
        for (int c = 0; c < 4; ++c) {
#pragma unroll
            for (int v = 0; v < 8; ++v) {
                const bf16x8 y = *(const bf16x8*)(&hbuf[(v * 16 + r) * H_STRIDE + c * 64 + q * 16]);
#pragma unroll
                for (int t = 0; t < 2; ++t)
                    acc[t][v] = __builtin_amdgcn_mfma_f32_16x16x32_bf16(A2[t][c], y, acc[t][v], 0, 0, 0);
            }
        }

        // ---- bias + relu + LN partials ----
        float s1[8], s2[8];
#pragma unroll
        for (int v = 0; v < 8; ++v) { s1[v] = 0.f; s2[v] = 0.f; }
#pragma unroll
        for (int t = 0; t < 2; ++t)
#pragma unroll
            for (int v = 0; v < 8; ++v) {
                f32x4 a = acc[t][v];
                a[0] = fmaxf(a[0] + b2v[t].x, 0.f);
                a[1] = fmaxf(a[1] + b2v[t].y, 0.f);
                a[2] = fmaxf(a[2] + b2v[t].z, 0.f);
                a[3] = fmaxf(a[3] + b2v[t].w, 0.f);
                acc[t][v] = a;
                s1[v] += a[0] + a[1] + a[2] + a[3];
                s2[v] += a[0] * a[0] + a[1] * a[1] + a[2] * a[2] + a[3] * a[3];
            }
#pragma unroll
        for (int v = 0; v < 8; ++v) {
            s1[v] += __shfl_xor(s1[v], 16);
            s1[v] += __shfl_xor(s1[v], 32);
            s2[v] += __shfl_xor(s2[v], 16);
            s2[v] += __shfl_xor(s2[v], 32);
        }
        if (lane < 16) {
#pragma unroll
            for (int v = 0; v < 8; ++v)
                lnp[wave][v][lane] = make_float2(s1[v], s2[v]);
        }
        __syncthreads();   // (3) partials ready

        // ---- finalize LN + fp32 stores ----
#pragma unroll
        for (int v = 0; v < 8; ++v) {
            float S1 = 0.f, S2 = 0.f;
#pragma unroll
            for (int w = 0; w < 4; ++w) {
                const float2 p = lnp[w][v][r];
                S1 += p.x; S2 += p.y;
            }
            const float mu  = S1 * (1.f / 128.f);
            const float var = S2 * (1.f / 128.f) - mu * mu;
            const float rs  = rsqrtf(var + LN_EPS);
            const int el = (v & 3) * 16 + r;            // edge within this iteration
            const bool ok = (e0 + el) < E;
            const long orow = ((v < 4) ? 0L : (long)E) + e0 + el;
#pragma unroll
            for (int t = 0; t < 2; ++t) {
                const int fq = wave * 32 + t * 16 + q * 4;
                const f32x4 a = acc[t][v];
                float4 o;
                o.x = (a[0] - mu) * rs * gv[t].x + bv[t].x;
                o.y = (a[1] - mu) * rs * gv[t].y + bv[t].y;
                o.z = (a[2] - mu) * rs * gv[t].z + bv[t].z;
                o.w = (a[3] - mu) * rs * gv[t].w + bv[t].w;
                if (ok)
                    *(float4*)(out + orow * 128 + fq) = o;
            }
        }
    }
}

extern "C" void kernel_launch(void* const* d_in, const int* in_sizes, int n_in,
                              void* d_out, int out_size, void* d_ws, size_t ws_size,
                              hipStream_t stream) {
    // Validated interface: dict order, fp32 inputs, fp32 output.
    const float* inR   = (const float*)d_in[0];
    const float* inL   = (const float*)d_in[1];
    const float* W1    = (const float*)d_in[2];
    const float* b1    = (const float*)d_in[3];
    const float* W2    = (const float*)d_in[4];
    const float* b2    = (const float*)d_in[5];
    const float* gamma = (const float*)d_in[6];
    const float* beta  = (const float*)d_in[7];
    const int E = in_sizes[0] / 128;

    const int niters = (E + 63) / 64;
    const int d = (niters + 2047) / 2048;        // tiles per block (balanced)
    const int grid = (niters + d - 1) / d;
    mpnn_mfma<<<grid, 256, 0, stream>>>(inR, inL, W1, b1, W2, b2, gamma, beta,
                                        (float*)d_out, E, niters);
}

// Round 20
// 243.831 us; speedup vs baseline: 1.7553x; 1.2802x over previous
//
#include <hip/hip_runtime.h>
#include <hip/hip_bf16.h>

#define LN_EPS 1e-5f

typedef __attribute__((ext_vector_type(8))) short bf16x8;
typedef __attribute__((ext_vector_type(4))) float f32x4;

__device__ __forceinline__ short f2bf(float x) {
    union { float f; unsigned u; } v; v.f = x;
    unsigned r = v.u + 0x7fff + ((v.u >> 16) & 1);   // RNE to bf16
    return (short)(r >> 16);
}

#define IN_STRIDE 528   // 512 data bytes + 16 pad
#define H_STRIDE  272   // 256 data bytes + 16 pad

// R12 schedule, 8-wave blocks: 512 threads, each wave owns 16 features
// (was 32) -> per-wave registers halve (~96+64 -> ~48+32), residency doubles
// (2 -> 4 waves/SIMD). Tile stays 32 edges; LDS layout and the 4-barrier
// structure are unchanged from R12 (the champion at 224 us).
// Each iteration: 32 edges -> 64 output rows (32 lr + 32 rl).
__global__ __launch_bounds__(512) void mpnn_mfma(
    const float* __restrict__ inR, const float* __restrict__ inL,
    const float* __restrict__ W1, const float* __restrict__ b1,
    const float* __restrict__ W2, const float* __restrict__ b2,
    const float* __restrict__ gamma, const float* __restrict__ beta,
    float* __restrict__ out, int E, int niters)
{
    __shared__ __align__(16) char inA[32 * IN_STRIDE];  // 32 edges x 256 k (bf16)
    __shared__ __align__(16) char hbuf[64 * H_STRIDE];  // 64 erows x 128 f (bf16)
    __shared__ float2 lnp[8][4][16];                    // [wave][v][r] = (sum, sumsq)

    const int tid  = threadIdx.x;
    const int lane = tid & 63;
    const int wave = tid >> 6;        // 0..7
    const int r    = lane & 15;
    const int q    = lane >> 4;

    // ---- weight fragments + per-feature vectors (once per block) ----
    // Wave w owns features [16w, 16w+16).
    bf16x8 A1[8], A2[4];
    float4 b1v, b2v, gv, bv;
    {
        const int fr = wave * 16 + r;        // A-operand row feature
#pragma unroll
        for (int c = 0; c < 8; ++c)
#pragma unroll
            for (int i = 0; i < 8; ++i)
                A1[c][i] = f2bf(W1[(c * 32 + q * 8 + i) * 128 + fr]);
#pragma unroll
        for (int c = 0; c < 4; ++c)
#pragma unroll
            for (int i = 0; i < 8; ++i)
                A2[c][i] = f2bf(W2[(c * 32 + q * 8 + i) * 128 + fr]);
        const int fq = wave * 16 + q * 4;    // D-row feature base
        b1v = *(const float4*)(b1 + fq);
        b2v = *(const float4*)(b2 + fq);
        gv  = *(const float4*)(gamma + fq);
        bv  = *(const float4*)(beta + fq);
    }

    for (int it = blockIdx.x; it < niters; it += gridDim.x) {
        const int e0 = it * 32;
        __syncthreads();   // (0) prev iteration's inA/lnp readers done

        // ---- stage 32 edges x 256 k as bf16 (fp32 loads, 16B LDS writes) ----
#pragma unroll
        for (int j = 0; j < 2; ++j) {
            const int idx = j * 512 + tid;       // [0,1024) = [e 0..31][hw][c8 0..15]
            const int e  = idx >> 5;
            const int hw = (idx >> 4) & 1;       // 0: left half (k<128), 1: right half
            const int c8 = idx & 15;             // 8-float group within half-row
            int ee = e0 + e; if (ee >= E) ee = E - 1;
            const float* src = hw ? inR : inL;   // msg = left || right
            const float4 v0 = *(const float4*)(src + (long)ee * 128 + c8 * 8);
            const float4 v1 = *(const float4*)(src + (long)ee * 128 + c8 * 8 + 4);
            bf16x8 s;
            s[0] = f2bf(v0.x); s[1] = f2bf(v0.y); s[2] = f2bf(v0.z); s[3] = f2bf(v0.w);
            s[4] = f2bf(v1.x); s[5] = f2bf(v1.y); s[6] = f2bf(v1.z); s[7] = f2bf(v1.w);
            *(bf16x8*)(&inA[e * IN_STRIDE + hw * 256 + c8 * 16]) = s;
        }
        __syncthreads();   // (1) inA ready

        // ---- layer 1: acc[v]: v=0,1 lr e-tiles; v=2,3 rl e-tiles ----
        f32x4 acc[4];
#pragma unroll
        for (int v = 0; v < 4; ++v)
            acc[v] = f32x4{0.f, 0.f, 0.f, 0.f};
#pragma unroll
        for (int c = 0; c < 8; ++c) {
            const bf16x8 x0 = *(const bf16x8*)(&inA[r        * IN_STRIDE + c * 64 + q * 16]);
            const bf16x8 x1 = *(const bf16x8*)(&inA[(16 + r) * IN_STRIDE + c * 64 + q * 16]);
            const int crl = (c + 4) & 7;
            acc[0] = __builtin_amdgcn_mfma_f32_16x16x32_bf16(A1[c],   x0, acc[0], 0, 0, 0);
            acc[1] = __builtin_amdgcn_mfma_f32_16x16x32_bf16(A1[c],   x1, acc[1], 0, 0, 0);
            acc[2] = __builtin_amdgcn_mfma_f32_16x16x32_bf16(A1[crl], x0, acc[2], 0, 0, 0);
            acc[3] = __builtin_amdgcn_mfma_f32_16x16x32_bf16(A1[crl], x1, acc[3], 0, 0, 0);
        }

        // ---- h1 = relu(. + b1) -> hbuf; erow: [0,32)=lr, [32,64)=rl ----
        {
            const int fq = wave * 16 + q * 4;
#pragma unroll
            for (int v = 0; v < 4; ++v) {
                const f32x4 a = acc[v];
                short4 s;
                s.x = f2bf(fmaxf(a[0] + b1v.x, 0.f));
                s.y = f2bf(fmaxf(a[1] + b1v.y, 0.f));
                s.z = f2bf(fmaxf(a[2] + b1v.z, 0.f));
                s.w = f2bf(fmaxf(a[3] + b1v.w, 0.f));
                *(short4*)(&hbuf[(v * 16 + r) * H_STRIDE + fq * 2]) = s;
            }
        }
        __syncthreads();   // (2) hbuf ready; all inA reads complete

        // ---- layer 2: reuse acc ----
#pragma unroll
        for (int v = 0; v < 4; ++v) acc[v] = f32x4{0.f, 0.f, 0.f, 0.f};
#pragma unroll
        for (int c = 0; c < 4; ++c) {
#pragma unroll
            for (int v = 0; v < 4; ++v) {
                const bf16x8 y = *(const bf16x8*)(&hbuf[(v * 16 + r) * H_STRIDE + c * 64 + q * 16]);
                acc[v] = __builtin_amdgcn_mfma_f32_16x16x32_bf16(A2[c], y, acc[v], 0, 0, 0);
            }
        }

        // ---- bias + relu + LN partials ----
        float s1[4], s2[4];
#pragma unroll
        for (int v = 0; v < 4; ++v) {
            f32x4 a = acc[v];
            a[0] = fmaxf(a[0] + b2v.x, 0.f);
            a[1] = fmaxf(a[1] + b2v.y, 0.f);
            a[2] = fmaxf(a[2] + b2v.z, 0.f);
            a[3] = fmaxf(a[3] + b2v.w, 0.f);
            acc[v] = a;
            s1[v] = a[0] + a[1] + a[2] + a[3];
            s2[v] = a[0] * a[0] + a[1] * a[1] + a[2] * a[2] + a[3] * a[3];
        }
#pragma unroll
        for (int v = 0; v < 4; ++v) {
            s1[v] += __shfl_xor(s1[v], 16);
            s1[v] += __shfl_xor(s1[v], 32);
            s2[v] += __shfl_xor(s2[v], 16);
            s2[v] += __shfl_xor(s2[v], 32);
        }
        if (lane < 16) {
#pragma unroll
            for (int v = 0; v < 4; ++v)
                lnp[wave][v][lane] = make_float2(s1[v], s2[v]);
        }
        __syncthreads();   // (3) partials ready

        // ---- finalize LN + fp32 stores ----
#pragma unroll
        for (int v = 0; v < 4; ++v) {
            float S1 = 0.f, S2 = 0.f;
#pragma unroll
            for (int w = 0; w < 8; ++w) {
                const float2 p = lnp[w][v][r];
                S1 += p.x; S2 += p.y;
            }
            const float mu  = S1 * (1.f / 128.f);
            const float var = S2 * (1.f / 128.f) - mu * mu;
            const float rs  = rsqrtf(var + LN_EPS);
            const int el = (v & 1) * 16 + r;            // edge within this iteration
            const bool ok = (e0 + el) < E;
            const long orow = ((v < 2) ? 0L : (long)E) + e0 + el;
            const int fq = wave * 16 + q * 4;
            const f32x4 a = acc[v];
            float4 o;
            o.x = (a[0] - mu) * rs * gv.x + bv.x;
            o.y = (a[1] - mu) * rs * gv.y + bv.y;
            o.z = (a[2] - mu) * rs * gv.z + bv.z;
            o.w = (a[3] - mu) * rs * gv.w + bv.w;
            if (ok)
                *(float4*)(out + orow * 128 + fq) = o;
        }
    }
}

extern "C" void kernel_launch(void* const* d_in, const int* in_sizes, int n_in,
                              void* d_out, int out_size, void* d_ws, size_t ws_size,
                              hipStream_t stream) {
    // Validated interface: dict order, fp32 inputs, fp32 output.
    const float* inR   = (const float*)d_in[0];
    const float* inL   = (const float*)d_in[1];
    const float* W1    = (const float*)d_in[2];
    const float* b1    = (const float*)d_in[3];
    const float* W2    = (const float*)d_in[4];
    const float* b2    = (const float*)d_in[5];
    const float* gamma = (const float*)d_in[6];
    const float* beta  = (const float*)d_in[7];
    const int E = in_sizes[0] / 128;

    const int niters = (E + 31) / 32;
    const int d = (niters + 2047) / 2048;        // tiles per block (balanced)
    const int grid = (niters + d - 1) / d;
    mpnn_mfma<<<grid, 512, 0, stream>>>(inR, inL, W1, b1, W2, b2, gamma, beta,
                                        (float*)d_out, E, niters);
}